// Round 1
// baseline (337.224 us; speedup 1.0000x reference)
//
#include <hip/hip_runtime.h>

// ---------- helpers ----------
static __device__ __forceinline__ void fma4(float4& a, float s, float4 v) {
  a.x = fmaf(s, v.x, a.x);
  a.y = fmaf(s, v.y, a.y);
  a.z = fmaf(s, v.z, a.z);
  a.w = fmaf(s, v.w, a.w);
}
static __device__ __forceinline__ float4 relu4(float4 a) {
  return make_float4(fmaxf(a.x, 0.f), fmaxf(a.y, 0.f),
                     fmaxf(a.z, 0.f), fmaxf(a.w, 0.f));
}

// ---------- transpose x (16,C,H,W) -> xt [C][H][W][16] ----------
// thread per (c,h,w) flat position p: coalesced reads across p, 4x float4 stores.
__global__ void k_transpose(const float* __restrict__ x, float* __restrict__ xt,
                            int chw, int total) {
  int p = blockIdx.x * blockDim.x + threadIdx.x;
  if (p >= total) return;
  float v[16];
#pragma unroll
  for (int b = 0; b < 16; ++b) v[b] = x[(size_t)b * chw + p];
  float4* o4 = reinterpret_cast<float4*>(xt) + (size_t)p * 4;
#pragma unroll
  for (int q = 0; q < 4; ++q)
    o4[q] = make_float4(v[4 * q + 0], v[4 * q + 1], v[4 * q + 2], v[4 * q + 3]);
}

// ---------- locally-connected conv (+bias+relu), stride S ----------
// xt  : [C][IH][IW][16]   (b fastest)
// wgt : [O][C][OH][OW][36]
// bias: [O][OH][OW]
// out : [O][OH][OW][16]
// thread t = bq + 4*(w + OW*(h + OH*o)); each thread computes 4 batch elems.
template <int C, int IH, int IW, int OH, int OW, int S>
__global__ void k_lc(const float* __restrict__ xt, const float* __restrict__ wgt,
                     const float* __restrict__ bias, float* __restrict__ out,
                     int total) {
  int t = blockIdx.x * blockDim.x + threadIdx.x;
  if (t >= total) return;
  int bq = t & 3;
  int p = t >> 2;
  int w = p % OW; p /= OW;
  int h = p % OH; p /= OH;
  int o = p;

  float bv = bias[(o * OH + h) * OW + w];
  float4 acc = make_float4(bv, bv, bv, bv);

  const float4* x4 = reinterpret_cast<const float4*>(xt);
  for (int c = 0; c < C; ++c) {
    const float4* wp = reinterpret_cast<const float4*>(wgt) +
                       ((size_t)((o * C + c) * OH + h) * OW + w) * 9;
    const float4* xc = x4 + ((size_t)(c * IH + h * S) * IW + w * S) * 4 + bq;
#pragma unroll
    for (int k4 = 0; k4 < 9; ++k4) {
      float4 wv = wp[k4];
#pragma unroll
      for (int r = 0; r < 4; ++r) {
        int k = k4 * 4 + r;
        int i = k / 6, j = k % 6;
        float4 xv = xc[(i * IW + j) * 4];
        float s = (r == 0) ? wv.x : (r == 1) ? wv.y : (r == 2) ? wv.z : wv.w;
        fma4(acc, s, xv);
      }
    }
  }
  reinterpret_cast<float4*>(out)[((size_t)(o * OH + h) * OW + w) * 4 + bq] =
      relu4(acc);
}

// ---------- 2x2 maxpool on [O][IH][IW][16] -> [O][PH][PW][16] ----------
__global__ void k_pool(const float* __restrict__ in, float* __restrict__ out,
                       int IH, int IW, int PH, int PW, int total) {
  int t = blockIdx.x * blockDim.x + threadIdx.x;
  if (t >= total) return;
  int bq = t & 3;
  int p = t >> 2;
  int w = p % PW; p /= PW;
  int h = p % PH; p /= PH;
  int o = p;
  const float4* in4 = reinterpret_cast<const float4*>(in);
  size_t r0 = ((size_t)(o * IH + 2 * h) * IW + 2 * w) * 4 + bq;
  float4 a = in4[r0];
  float4 b = in4[r0 + 4];
  float4 c = in4[r0 + (size_t)IW * 4];
  float4 d = in4[r0 + (size_t)IW * 4 + 4];
  float4 m;
  m.x = fmaxf(fmaxf(a.x, b.x), fmaxf(c.x, d.x));
  m.y = fmaxf(fmaxf(a.y, b.y), fmaxf(c.y, d.y));
  m.z = fmaxf(fmaxf(a.z, b.z), fmaxf(c.z, d.z));
  m.w = fmaxf(fmaxf(a.w, b.w), fmaxf(c.w, d.w));
  reinterpret_cast<float4*>(out)[((size_t)(o * PH + h) * PW + w) * 4 + bq] = m;
}

// ---------- FC stage 1: partial dot products over j-chunks ----------
// a3  : [6144][16]  (j, b)  -- exactly L3 output layout
// wf  : [10178][6144]
// part: [JC][10178][16]
constexpr int FC_N = 10178;
constexpr int FC_K = 6144;
constexpr int FC_JC = 16;              // j chunks
constexpr int FC_JLEN = FC_K / FC_JC;  // 384
constexpr int FC_NB = 4;               // n rows per thread
constexpr int FC_NG = (FC_N + FC_NB - 1) / FC_NB;  // 2545

__global__ void k_fc1(const float* __restrict__ a3, const float* __restrict__ wf,
                      float* __restrict__ part, int total) {
  int t = blockIdx.x * blockDim.x + threadIdx.x;
  if (t >= total) return;
  int bq = t & 3;
  int p = t >> 2;
  int ng = p % FC_NG;
  int jc = p / FC_NG;
  int n0 = ng * FC_NB;
  int jbase = jc * FC_JLEN;

  const float4* x4 = reinterpret_cast<const float4*>(a3);
  float4 acc[FC_NB];
#pragma unroll
  for (int m = 0; m < FC_NB; ++m) acc[m] = make_float4(0.f, 0.f, 0.f, 0.f);

  for (int q = 0; q < FC_JLEN / 4; ++q) {
    float4 xv[4];
#pragma unroll
    for (int r = 0; r < 4; ++r)
      xv[r] = x4[(size_t)(jbase + q * 4 + r) * 4 + bq];
#pragma unroll
    for (int m = 0; m < FC_NB; ++m) {
      int n = n0 + m;
      if (n > FC_N - 1) n = FC_N - 1;  // clamp (store is guarded)
      float4 wv = *reinterpret_cast<const float4*>(wf + (size_t)n * FC_K +
                                                   jbase + q * 4);
      fma4(acc[m], wv.x, xv[0]);
      fma4(acc[m], wv.y, xv[1]);
      fma4(acc[m], wv.z, xv[2]);
      fma4(acc[m], wv.w, xv[3]);
    }
  }
#pragma unroll
  for (int m = 0; m < FC_NB; ++m) {
    int n = n0 + m;
    if (n < FC_N)
      reinterpret_cast<float4*>(part)[((size_t)jc * FC_N + n) * 4 + bq] = acc[m];
  }
}

// ---------- FC stage 2: reduce chunks + bias, write (16,10178) ----------
__global__ void k_fc2(const float* __restrict__ part, const float* __restrict__ bf,
                      float* __restrict__ out, int total) {
  int t = blockIdx.x * blockDim.x + threadIdx.x;
  if (t >= total) return;
  int bq = t & 3;
  int n = t >> 2;
  float bv = bf[n];
  float4 acc = make_float4(bv, bv, bv, bv);
  const float4* p4 = reinterpret_cast<const float4*>(part);
#pragma unroll
  for (int jc = 0; jc < FC_JC; ++jc) {
    float4 v = p4[((size_t)jc * FC_N + n) * 4 + bq];
    acc.x += v.x; acc.y += v.y; acc.z += v.z; acc.w += v.w;
  }
  out[(size_t)(4 * bq + 0) * FC_N + n] = acc.x;
  out[(size_t)(4 * bq + 1) * FC_N + n] = acc.y;
  out[(size_t)(4 * bq + 2) * FC_N + n] = acc.z;
  out[(size_t)(4 * bq + 3) * FC_N + n] = acc.w;
}

// ---------- launch ----------
static inline int cdiv(int a, int b) { return (a + b - 1) / b; }

extern "C" void kernel_launch(void* const* d_in, const int* in_sizes, int n_in,
                              void* d_out, int out_size, void* d_ws,
                              size_t ws_size, hipStream_t stream) {
  const float* x  = (const float*)d_in[0];  // (16,3,218,178)
  const float* w1 = (const float*)d_in[1];  // (8,3,213,173,36)
  const float* b1 = (const float*)d_in[2];  // (8,213,173)
  const float* w2 = (const float*)d_in[3];  // (16,8,51,41,36)
  const float* b2 = (const float*)d_in[4];  // (16,51,41)
  const float* w3 = (const float*)d_in[5];  // (32,16,16,12,36)
  const float* b3 = (const float*)d_in[6];  // (32,16,12)
  const float* wf = (const float*)d_in[7];  // (10178,6144)
  const float* bf = (const float*)d_in[8];  // (10178,)
  float* out = (float*)d_out;               // (16,10178)

  float* ws = (float*)d_ws;
  // workspace layout (float offsets, all multiples of 16)
  float* xt   = ws;                       // 3*218*178*16      = 1,862,592
  float* a1   = xt + 1862592;             // 8*213*173*16      = 4,716,672
  float* a1p  = a1 + 4716672;             // 8*106*86*16       = 1,166,848
  float* a2   = a1p + 1166848;            // 16*51*41*16       =   535,296
  float* a3   = a2 + 535296;              // 32*16*12*16       =    98,304
  float* part = a3 + 98304;               // 16*10178*16       = 2,605,568

  const int B = 256;

  // transpose x -> xt
  {
    int total = 3 * 218 * 178;  // thread per (c,h,w)
    k_transpose<<<cdiv(total, B), B, 0, stream>>>(x, xt, total, total);
  }
  // L1: lc2d stride 1, O=8, out 213x173
  {
    int total = 4 * 8 * 213 * 173;
    k_lc<3, 218, 178, 213, 173, 1>
        <<<cdiv(total, B), B, 0, stream>>>(xt, w1, b1, a1, total);
  }
  // maxpool2 -> 106x86
  {
    int total = 4 * 8 * 106 * 86;
    k_pool<<<cdiv(total, B), B, 0, stream>>>(a1, a1p, 213, 173, 106, 86, total);
  }
  // L2: lc2d stride 2, C=8 -> O=16, out 51x41
  {
    int total = 4 * 16 * 51 * 41;
    k_lc<8, 106, 86, 51, 41, 2>
        <<<cdiv(total, B), B, 0, stream>>>(a1p, w2, b2, a2, total);
  }
  // L3: lc2d stride 3, C=16 -> O=32, out 16x12
  {
    int total = 4 * 32 * 16 * 12;
    k_lc<16, 51, 41, 16, 12, 3>
        <<<cdiv(total, B), B, 0, stream>>>(a2, w3, b3, a3, total);
  }
  // FC stage 1: partials over 16 j-chunks
  {
    int total = 4 * FC_NG * FC_JC;
    k_fc1<<<cdiv(total, B), B, 0, stream>>>(a3, wf, part, total);
  }
  // FC stage 2: reduce + bias
  {
    int total = 4 * FC_N;
    k_fc2<<<cdiv(total, B), B, 0, stream>>>(part, bf, out, total);
  }
}